// Round 3
// baseline (1185.336 us; speedup 1.0000x reference)
//
#include <hip/hip_runtime.h>
#include <math.h>

#define BB 4
#define CC0 32
#define HH 320
#define WW 640
#define HWp (HH*WW)          // 204800
#define CHWp (CC0*HWp)       // 6553600
#define NCH (BB*HWp)         // 819200
#define CCAT 128

// ---------------- workspace layout ----------------
// wbf (ushort, MFMA B-frag order): 36864 ushorts at float-offset 0 (73728 B)
// st  floats [36864,37184): s1[128] q1[128] s2[32] q2[32]
// sc  floats [37184,37504): scale1[128] shift1[128] scale2[32] shift2[32]
// cat bf16 channel-last [b][pix][128]: 104,857,600 elems from float-offset 37504
#define WT_OFF  ((size_t)0)
#define ST_OFF  ((size_t)36864)
#define SC_OFF  ((size_t)37184)
#define CATF_OFF ((size_t)37504)

typedef unsigned short ushort_t;
typedef __attribute__((ext_vector_type(8)))  short  short8;
typedef __attribute__((ext_vector_type(16))) float  float16v;
typedef __attribute__((ext_vector_type(4)))  unsigned uintv4;   // native vec for NT stores

static __device__ __forceinline__ float bf2f(ushort_t u) {
  unsigned x = ((unsigned)u) << 16;
  float f; __builtin_memcpy(&f, &x, 4); return f;
}
static __device__ __forceinline__ ushort_t f2bf(float f) {
  unsigned x; __builtin_memcpy(&x, &f, 4);
  unsigned r = (x + 0x7fffu + ((x >> 16) & 1u)) >> 16;   // RNE
  return (ushort_t)r;
}
static __device__ __forceinline__ unsigned pack2(float a, float b) {
  return (unsigned)f2bf(a) | ((unsigned)f2bf(b) << 16);
}
static __device__ __forceinline__ void unpack8(uint4 u, float* f) {
  f[0] = bf2f((ushort_t)(u.x & 0xffff)); f[1] = bf2f((ushort_t)(u.x >> 16));
  f[2] = bf2f((ushort_t)(u.y & 0xffff)); f[3] = bf2f((ushort_t)(u.y >> 16));
  f[4] = bf2f((ushort_t)(u.z & 0xffff)); f[5] = bf2f((ushort_t)(u.z >> 16));
  f[6] = bf2f((ushort_t)(u.w & 0xffff)); f[7] = bf2f((ushort_t)(u.w >> 16));
}

// ---------------- 1. L2 normalize -> fp32 channel-LAST xn (into d_out) -------
// fp32 keeps the branch kernel unpack-free; 105 MB fits the 256 MB L3.
__global__ __launch_bounds__(256) void k_normalize(const float* __restrict__ x,
                                                   float* __restrict__ xnf) {
  int p2 = blockIdx.x * 256 + threadIdx.x;     // pixel-pair index
  int b  = blockIdx.y;
  const float2* xp = (const float2*)(x + (size_t)b * CHWp) + p2;
  float va[32], vb[32];
  float sa = 0.f, sb = 0.f;
  #pragma unroll
  for (int c = 0; c < 32; ++c) {
    float2 v = xp[c * (HWp/2)];
    va[c] = v.x; vb[c] = v.y;
    sa = fmaf(v.x, v.x, sa); sb = fmaf(v.y, v.y, sb);
  }
  float ia = 1.f / fmaxf(sqrtf(sa), 1e-12f);
  float ib = 1.f / fmaxf(sqrtf(sb), 1e-12f);
  float4* op = (float4*)(xnf + ((size_t)b * HWp + (size_t)p2 * 2) * 32);
  #pragma unroll
  for (int q = 0; q < 8; ++q) {
    float4 u;
    u.x = va[q*4+0]*ia; u.y = va[q*4+1]*ia;
    u.z = va[q*4+2]*ia; u.w = va[q*4+3]*ia;
    op[q] = u;
  }
  #pragma unroll
  for (int q = 0; q < 8; ++q) {
    float4 u;
    u.x = vb[q*4+0]*ib; u.y = vb[q*4+1]*ib;
    u.z = vb[q*4+2]*ib; u.w = vb[q*4+3]*ib;
    op[8 + q] = u;
  }
}

// ---------------- 2. affinity + 8->32 matmul, one dilation per z-block -------
// z-in-grid for TLP (12800 blocks). fp32 loads: zero unpack VALU. NT stores
// for cat keep the streamed output from evicting xn out of L2/L3.
__global__ __launch_bounds__(256, 4) void k_branch(const float* __restrict__ xnf,
                                                   const float* __restrict__ w0,
                                                   const float* __restrict__ w1,
                                                   const float* __restrict__ w2,
                                                   const float* __restrict__ w3,
                                                   ushort_t* __restrict__ cat) {
  int z = blockIdx.z;
  int d = 1 << z;
  const float* w = (z == 0) ? w0 : (z == 1) ? w1 : (z == 2) ? w2 : w3;
  int bx = blockIdx.x;
  bx = (bx & 7) * 100 + (bx >> 3);       // 800 = 8 XCDs * 100 contiguous chunks
  int pix = bx * 256 + threadIdx.x;
  int b   = blockIdx.y;
  int y = pix / WW;
  int x = pix - y * WW;

  const float* cp0 = xnf + ((size_t)b * HWp + pix) * 32;
  float4 cen[8];
  {
    const float4* cv = (const float4*)cp0;
    #pragma unroll
    for (int q = 0; q < 8; ++q) cen[q] = cv[q];
  }

  const int DY[8] = {-1,-1,-1, 0, 0, 1, 1, 1};
  const int DX[8] = {-1, 0, 1,-1, 1,-1, 0, 1};
  float a[8];
  #pragma unroll
  for (int k = 0; k < 8; ++k) {
    int dy = DY[k] * d, dx = DX[k] * d;
    bool ok = ((unsigned)(y + dy) < (unsigned)HH) && ((unsigned)(x + dx) < (unsigned)WW);
    int ofs = ok ? (dy * WW + dx) : 0;     // OOB -> read own pixel, masked
    const float4* np = (const float4*)(cp0 + (ptrdiff_t)ofs * 32);
    float a0 = 0.f, a1 = 0.f, a2 = 0.f, a3 = 0.f;   // break the 32-deep chain
    #pragma unroll
    for (int q = 0; q < 8; ++q) {
      float4 n = np[q];
      a0 = fmaf(cen[q].x, n.x, a0);
      a1 = fmaf(cen[q].y, n.y, a1);
      a2 = fmaf(cen[q].z, n.z, a2);
      a3 = fmaf(cen[q].w, n.w, a3);
    }
    float acc = (a0 + a1) + (a2 + a3);
    a[k] = ok ? fmaxf(acc, 0.f) : 0.f;
  }

  uintv4* cp = (uintv4*)(cat + ((size_t)b * HWp + pix) * 128 + z * 32);
  #pragma unroll
  for (int q = 0; q < 4; ++q) {
    unsigned pw[4];
    #pragma unroll
    for (int pp = 0; pp < 4; ++pp) {
      int o = q * 8 + pp * 2;
      float h0 = 0.f, h1 = 0.f;
      #pragma unroll
      for (int k = 0; k < 8; ++k) {
        h0 = fmaf(a[k], w[o * 8 + k], h0);
        h1 = fmaf(a[k], w[(o + 1) * 8 + k], h1);
      }
      pw[pp] = pack2(h0, h1);
    }
    uintv4 u;
    u.x = pw[0]; u.y = pw[1]; u.z = pw[2]; u.w = pw[3];
    __builtin_nontemporal_store(u, cp + q);
  }
}

// ---------------- 3a. per-channel stats over channel-last bf16 cat -----------
// uint4 loads: 8 ch/thread, wave reads 1KB contiguous per instruction
__global__ __launch_bounds__(256) void k_stats_cat(const ushort_t* __restrict__ cat,
                                                   float* __restrict__ g_s,
                                                   float* __restrict__ g_q) {
  int t  = threadIdx.x;
  int cg = t & 15;              // channel group: ch = cg*8
  int pr = t >> 4;              // 16 pixel streams
  size_t pix0 = (size_t)blockIdx.x * 2048 + pr;
  const uint4* base = (const uint4*)cat;     // 16B = 8 channels
  float s[8] = {0,0,0,0,0,0,0,0}, q[8] = {0,0,0,0,0,0,0,0};
  for (int j = 0; j < 128; ++j) {
    size_t pix = pix0 + (size_t)j * 16;
    uint4 u = base[pix * 16 + cg];
    float v[8]; unpack8(u, v);
    #pragma unroll
    for (int i = 0; i < 8; ++i) { s[i] += v[i]; q[i] = fmaf(v[i], v[i], q[i]); }
  }
  __shared__ float ls[16][128], lq[16][128];
  #pragma unroll
  for (int i = 0; i < 8; ++i) { ls[pr][cg*8+i] = s[i]; lq[pr][cg*8+i] = q[i]; }
  __syncthreads();
  if (t < 128) {
    float a = 0.f, bq = 0.f;
    #pragma unroll
    for (int r = 0; r < 16; ++r) { a += ls[r][t]; bq += lq[r][t]; }
    atomicAdd(g_s + t, a); atomicAdd(g_q + t, bq);
  }
}

// ---------------- 3b. per-channel stats over fp32 channel-first tensor -------
__global__ __launch_bounds__(256) void k_stats_f32(const float* __restrict__ t,
                                                   float* __restrict__ g_s,
                                                   float* __restrict__ g_q) {
  int c = blockIdx.y, b = blockIdx.z;
  size_t base = ((size_t)b * 32 + c) * HWp + (size_t)blockIdx.x * 8192;
  const float4* p = (const float4*)(t + base) + threadIdx.x;
  float s = 0.f, q = 0.f;
  #pragma unroll
  for (int j = 0; j < 8; ++j) {
    float4 v = p[j * 256];
    s += v.x + v.y + v.z + v.w;
    q = fmaf(v.x, v.x, q); q = fmaf(v.y, v.y, q);
    q = fmaf(v.z, v.z, q); q = fmaf(v.w, v.w, q);
  }
  #pragma unroll
  for (int off = 32; off > 0; off >>= 1) {
    s += __shfl_down(s, off, 64);
    q += __shfl_down(q, off, 64);
  }
  __shared__ float ls[4], lq[4];
  int lane = threadIdx.x & 63, wid = threadIdx.x >> 6;
  if (lane == 0) { ls[wid] = s; lq[wid] = q; }
  __syncthreads();
  if (threadIdx.x == 0) {
    float ts = 0, tq = 0;
    #pragma unroll
    for (int i = 0; i < 4; ++i) { ts += ls[i]; tq += lq[i]; }
    atomicAdd(g_s + c, ts); atomicAdd(g_q + c, tq);
  }
}

// ---------------- 4. finalize BN scale/shift ----------------
__global__ void k_bnfin(const float* __restrict__ s, const float* __restrict__ q,
                        const float* g0, const float* g1, const float* g2, const float* g3,
                        const float* b0, const float* b1, const float* b2, const float* b3,
                        float* __restrict__ scale, float* __restrict__ shift, int Cc) {
  int c = threadIdx.x;
  if (c >= Cc) return;
  const float* g; const float* bb; int ci;
  if (Cc == 128) {
    int z = c >> 5; ci = c & 31;
    g  = (z == 0) ? g0 : (z == 1) ? g1 : (z == 2) ? g2 : g3;
    bb = (z == 0) ? b0 : (z == 1) ? b1 : (z == 2) ? b2 : b3;
  } else { g = g0; bb = b0; ci = c; }
  float mean = s[c] / (float)NCH;
  float var  = q[c] / (float)NCH - mean * mean;
  float inv  = 1.f / sqrtf(var + 1e-5f);
  float scv  = g[ci] * inv;
  scale[c] = scv;
  shift[c] = bb[ci] - mean * scv;
}

// ---------------- 5. weights -> bf16 MFMA B-fragment order -------------------
// wbf[((t*8 + cg)*64 + lane)*8 + j] = W[o=lane&31][ch=cg*16+(lane>>5)*8+j][tap t]
__global__ void k_wt(const float* __restrict__ wl, ushort_t* __restrict__ wbf) {
  int idx = blockIdx.x * 256 + threadIdx.x;
  if (idx >= 9 * 8 * 64 * 8) return;
  int j = idx & 7;
  int l = (idx >> 3) & 63;
  int tc = idx >> 9;                 // t*8 + cg
  int t = tc >> 3, cg = tc & 7;
  int o = l & 31;
  int ch = cg * 16 + ((l >> 5) << 3) + j;
  wbf[idx] = f2bf(wl[(o * 128 + ch) * 9 + t]);
}

// ---------------- 6. MFMA implicit-GEMM 3x3 conv 128->32 ---------------------
#define SROWS 6
#define SCOLS 34
#define CHPAD 72
__global__ __launch_bounds__(256, 4) void k_conv(const ushort_t* __restrict__ cat,
                                                 const ushort_t* __restrict__ wbf,
                                                 const float* __restrict__ scale,
                                                 const float* __restrict__ shift,
                                                 float* __restrict__ out) {
  __shared__ __align__(16) ushort_t s_in[SROWS * SCOLS * CHPAD];  // 29376 B
  int lane = threadIdx.x;            // 0..63
  int w    = threadIdx.y;            // 0..3
  int tid  = w * 64 + lane;
  int gx0 = blockIdx.x * 32, gy0 = blockIdx.y * 4;
  int b = blockIdx.z;
  size_t bHW = (size_t)b * HWp;

  const short8* wfr = (const short8*)wbf;
  float16v acc = {};

  int site0 = tid >> 3;              // 0..31
  int chp   = tid & 7;               // 16B chunk within 64 staged channels

  #pragma unroll
  for (int r = 0; r < 2; ++r) {
    int chb = r * 64 + chp * 8;
    float4 sc0 = *(const float4*)&scale[chb];
    float4 sc1 = *(const float4*)&scale[chb + 4];
    float4 sh0 = *(const float4*)&shift[chb];
    float4 sh1 = *(const float4*)&shift[chb + 4];
    float scl[8] = {sc0.x,sc0.y,sc0.z,sc0.w,sc1.x,sc1.y,sc1.z,sc1.w};
    float shf[8] = {sh0.x,sh0.y,sh0.z,sh0.w,sh1.x,sh1.y,sh1.z,sh1.w};

    if (r) __syncthreads();
    for (int s = site0; s < SROWS * SCOLS; s += 32) {
      int row = s / SCOLS, col = s - row * SCOLS;
      int gy = gy0 - 1 + row, gx = gx0 - 1 + col;
      uint4 u = {0u,0u,0u,0u};
      if ((unsigned)gy < (unsigned)HH && (unsigned)gx < (unsigned)WW) {
        uint4 raw = *(const uint4*)&cat[(bHW + (size_t)gy * WW + gx) * 128 + chb];
        unsigned rw[4] = {raw.x, raw.y, raw.z, raw.w};
        unsigned pk[4];
        #pragma unroll
        for (int q = 0; q < 4; ++q) {
          float v0 = fmaxf(fmaf(bf2f((ushort_t)(rw[q] & 0xffff)), scl[q*2],   shf[q*2]),   0.f);
          float v1 = fmaxf(fmaf(bf2f((ushort_t)(rw[q] >> 16)),    scl[q*2+1], shf[q*2+1]), 0.f);
          pk[q] = pack2(v0, v1);
        }
        u.x = pk[0]; u.y = pk[1]; u.z = pk[2]; u.w = pk[3];
      }
      *(uint4*)&s_in[(size_t)s * CHPAD + chp * 8] = u;
    }
    __syncthreads();

    int pcol = lane & 31;
    int half = lane >> 5;
    #pragma unroll
    for (int t = 0; t < 9; ++t) {
      int ky = t / 3, kx = t - ky * 3;
      int rowbase = ((w + ky) * SCOLS + pcol + kx) * CHPAD + half * 8;
      #pragma unroll
      for (int c = 0; c < 4; ++c) {
        short8 bfrag = wfr[(t * 8 + r * 4 + c) * 64 + lane];
        short8 afrag = *(const short8*)&s_in[rowbase + c * 16];
        acc = __builtin_amdgcn_mfma_f32_32x32x16_bf16(afrag, bfrag, acc, 0, 0, 0);
      }
    }
  }

  // epilogue: transpose C tile through LDS for coalesced channel-first stores
  __syncthreads();
  float* epi = (float*)s_in + w * (32 * 33);
  int half = lane >> 5, mm = lane & 31;
  #pragma unroll
  for (int r16 = 0; r16 < 16; ++r16) {
    int m = (r16 & 3) + 8 * (r16 >> 2) + 4 * half;
    epi[m * 33 + mm] = acc[r16];
  }
  __syncthreads();
  size_t obase = bHW + (size_t)(gy0 + w) * WW + gx0 + mm;
  #pragma unroll
  for (int i = 0; i < 16; ++i) {
    int o = half * 16 + i;
    out[(size_t)o * HWp + obase + (size_t)b * (CHWp - HWp)] = epi[mm * 33 + o];
  }
}

// ---------------- 7. BN2 + ReLU + 32x32 matmul, in-place on d_out ------------
// float2: 2 pixels per thread
__global__ __launch_bounds__(256) void k_final(const float* hin,
                                               const float* __restrict__ wf,
                                               const float* __restrict__ scale,
                                               const float* __restrict__ shift,
                                               float* out) {
  int p2 = blockIdx.x * 256 + threadIdx.x;
  int b  = blockIdx.y;
  const float2* hp = (const float2*)(hin + (size_t)b * CHWp) + p2;
  float va[32], vb[32];
  #pragma unroll
  for (int c = 0; c < 32; ++c) {
    float2 v = hp[c * (HWp/2)];
    va[c] = fmaxf(fmaf(v.x, scale[c], shift[c]), 0.f);
    vb[c] = fmaxf(fmaf(v.y, scale[c], shift[c]), 0.f);
  }
  float2* op = (float2*)(out + (size_t)b * CHWp) + p2;
  #pragma unroll
  for (int o = 0; o < 32; ++o) {
    float ra = 0.f, rb = 0.f;
    #pragma unroll
    for (int c = 0; c < 32; ++c) {
      float wv = wf[o * 32 + c];
      ra = fmaf(va[c], wv, ra);
      rb = fmaf(vb[c], wv, rb);
    }
    float2 rr; rr.x = ra; rr.y = rb;
    op[o * (HWp/2)] = rr;
  }
}

extern "C" void kernel_launch(void* const* d_in, const int* in_sizes, int n_in,
                              void* d_out, int out_size, void* d_ws, size_t ws_size,
                              hipStream_t stream) {
  const float* x      = (const float*)d_in[0];
  const float* w1     = (const float*)d_in[1];
  const float* g1     = (const float*)d_in[2];
  const float* b1     = (const float*)d_in[3];
  const float* w2     = (const float*)d_in[4];
  const float* g2     = (const float*)d_in[5];
  const float* b2     = (const float*)d_in[6];
  const float* w3     = (const float*)d_in[7];
  const float* g3     = (const float*)d_in[8];
  const float* b3     = (const float*)d_in[9];
  const float* w4     = (const float*)d_in[10];
  const float* g4     = (const float*)d_in[11];
  const float* b4     = (const float*)d_in[12];
  const float* w_last = (const float*)d_in[13];
  const float* g_last = (const float*)d_in[14];
  const float* b_last = (const float*)d_in[15];
  const float* w_fin  = (const float*)d_in[16];

  float* ws = (float*)d_ws;
  ushort_t* wbf = (ushort_t*)(ws + WT_OFF);
  float*    st  = ws + ST_OFF;
  float*    sc  = ws + SC_OFF;
  ushort_t* cat = (ushort_t*)(ws + CATF_OFF);

  float* xn = (float*)d_out;  // d_out: fp32 xn -> fp32 conv-out -> final out

  hipMemsetAsync(st, 0, 320 * sizeof(float), stream);

  k_normalize<<<dim3(400, 4), 256, 0, stream>>>(x, xn);
  k_branch<<<dim3(800, 4, 4), 256, 0, stream>>>(xn, w1, w2, w3, w4, cat);
  k_stats_cat<<<400, 256, 0, stream>>>(cat, st, st + 128);
  k_bnfin<<<1, 128, 0, stream>>>(st, st + 128, g1, g2, g3, g4, b1, b2, b3, b4,
                                 sc, sc + 128, 128);
  k_wt<<<144, 256, 0, stream>>>(w_last, wbf);
  k_conv<<<dim3(20, 80, 4), dim3(64, 4), 0, stream>>>(cat, wbf, sc, sc + 128, xn);
  k_stats_f32<<<dim3(25, 32, 4), 256, 0, stream>>>(xn, st + 256, st + 288);
  k_bnfin<<<1, 128, 0, stream>>>(st + 256, st + 288, g_last, g_last, g_last, g_last,
                                 b_last, b_last, b_last, b_last, sc + 256, sc + 288, 32);
  k_final<<<dim3(400, 4), 256, 0, stream>>>(xn, w_fin, sc + 256, sc + 288, (float*)d_out);
}

// Round 4
// 1076.942 us; speedup vs baseline: 1.1006x; 1.1006x over previous
//
#include <hip/hip_runtime.h>
#include <math.h>

#define BB 4
#define CC0 32
#define HH 320
#define WW 640
#define HWp (HH*WW)          // 204800
#define CHWp (CC0*HWp)       // 6553600
#define NCH (BB*HWp)         // 819200
#define CCAT 128

// ---------------- workspace layout ----------------
// wbf (ushort, MFMA B-frag order): 36864 ushorts at float-offset 0 (73728 B)
// st  floats [36864,37184): s1[128] q1[128] s2[32] q2[32]
// sc  floats [37184,37504): scale1[128] shift1[128] scale2[32] shift2[32]
// cat bf16 SPLIT PLANES [z][b][pix][32]: 104,857,600 elems from float-offset 37504
//     (plane z base: z * NCH * 32 ushorts; full-line streaming writes per thread)
#define WT_OFF  ((size_t)0)
#define ST_OFF  ((size_t)36864)
#define SC_OFF  ((size_t)37184)
#define CATF_OFF ((size_t)37504)

typedef unsigned short ushort_t;
typedef __attribute__((ext_vector_type(8)))  short  short8;
typedef __attribute__((ext_vector_type(16))) float  float16v;

static __device__ __forceinline__ float bf2f(ushort_t u) {
  unsigned x = ((unsigned)u) << 16;
  float f; __builtin_memcpy(&f, &x, 4); return f;
}
static __device__ __forceinline__ ushort_t f2bf(float f) {
  unsigned x; __builtin_memcpy(&x, &f, 4);
  unsigned r = (x + 0x7fffu + ((x >> 16) & 1u)) >> 16;   // RNE
  return (ushort_t)r;
}
static __device__ __forceinline__ unsigned pack2(float a, float b) {
  return (unsigned)f2bf(a) | ((unsigned)f2bf(b) << 16);
}
static __device__ __forceinline__ void unpack8(uint4 u, float* f) {
  f[0] = bf2f((ushort_t)(u.x & 0xffff)); f[1] = bf2f((ushort_t)(u.x >> 16));
  f[2] = bf2f((ushort_t)(u.y & 0xffff)); f[3] = bf2f((ushort_t)(u.y >> 16));
  f[4] = bf2f((ushort_t)(u.z & 0xffff)); f[5] = bf2f((ushort_t)(u.z >> 16));
  f[6] = bf2f((ushort_t)(u.w & 0xffff)); f[7] = bf2f((ushort_t)(u.w >> 16));
}

// ---------------- 1. L2 normalize -> fp32 channel-LAST xn (into d_out) -------
// fp32 keeps the branch kernel unpack-free; swizzle + L2/L3 absorb refetch.
__global__ __launch_bounds__(256) void k_normalize(const float* __restrict__ x,
                                                   float* __restrict__ xnf) {
  int p2 = blockIdx.x * 256 + threadIdx.x;     // pixel-pair index
  int b  = blockIdx.y;
  const float2* xp = (const float2*)(x + (size_t)b * CHWp) + p2;
  float va[32], vb[32];
  float sa = 0.f, sb = 0.f;
  #pragma unroll
  for (int c = 0; c < 32; ++c) {
    float2 v = xp[c * (HWp/2)];
    va[c] = v.x; vb[c] = v.y;
    sa = fmaf(v.x, v.x, sa); sb = fmaf(v.y, v.y, sb);
  }
  float ia = 1.f / fmaxf(sqrtf(sa), 1e-12f);
  float ib = 1.f / fmaxf(sqrtf(sb), 1e-12f);
  float4* op = (float4*)(xnf + ((size_t)b * HWp + (size_t)p2 * 2) * 32);
  #pragma unroll
  for (int q = 0; q < 8; ++q) {
    float4 u;
    u.x = va[q*4+0]*ia; u.y = va[q*4+1]*ia;
    u.z = va[q*4+2]*ia; u.w = va[q*4+3]*ia;
    op[q] = u;
  }
  #pragma unroll
  for (int q = 0; q < 8; ++q) {
    float4 u;
    u.x = vb[q*4+0]*ib; u.y = vb[q*4+1]*ib;
    u.z = vb[q*4+2]*ib; u.w = vb[q*4+3]*ib;
    op[8 + q] = u;
  }
}

// ---------------- 2. FUSED affinity + 8->32 matmul, ALL 4 dilations ----------
// One thread = one pixel, all dilations. xn read ONCE per pixel (center reg-
// cached, taps L1/L2-reused across z). Split-plane cat: each z writes a full
// contiguous 64B line per pixel -> no partial-line write amplification.
__global__ __launch_bounds__(256) void k_branch_all(const float* __restrict__ xnf,
                                                    const float* __restrict__ w0,
                                                    const float* __restrict__ w1,
                                                    const float* __restrict__ w2,
                                                    const float* __restrict__ w3,
                                                    ushort_t* __restrict__ cat) {
  int bx = blockIdx.x;
  bx = (bx & 7) * 100 + (bx >> 3);       // 800 = 8 XCDs * 100 contiguous chunks
  int pix = bx * 256 + threadIdx.x;
  int b   = blockIdx.y;
  int y = pix / WW;
  int x = pix - y * WW;

  const float* cp0 = xnf + ((size_t)b * HWp + pix) * 32;
  float4 cen[8];
  {
    const float4* cv = (const float4*)cp0;
    #pragma unroll
    for (int q = 0; q < 8; ++q) cen[q] = cv[q];
  }

  const int DY[8] = {-1,-1,-1, 0, 0, 1, 1, 1};
  const int DX[8] = {-1, 0, 1,-1, 1,-1, 0, 1};

  #pragma unroll 1
  for (int z = 0; z < 4; ++z) {
    int d = 1 << z;
    const float* w = (z == 0) ? w0 : (z == 1) ? w1 : (z == 2) ? w2 : w3;
    float a[8];
    #pragma unroll
    for (int k = 0; k < 8; ++k) {
      int dy = DY[k] * d, dx = DX[k] * d;
      bool ok = ((unsigned)(y + dy) < (unsigned)HH) && ((unsigned)(x + dx) < (unsigned)WW);
      int ofs = ok ? (dy * WW + dx) : 0;     // OOB -> read own pixel, masked
      const float4* np = (const float4*)(cp0 + (ptrdiff_t)ofs * 32);
      float a0 = 0.f, a1 = 0.f, a2 = 0.f, a3 = 0.f;   // 4 partials: short dep chains
      #pragma unroll
      for (int q = 0; q < 8; ++q) {
        float4 n = np[q];
        a0 = fmaf(cen[q].x, n.x, a0);
        a1 = fmaf(cen[q].y, n.y, a1);
        a2 = fmaf(cen[q].z, n.z, a2);
        a3 = fmaf(cen[q].w, n.w, a3);
      }
      float acc = (a0 + a1) + (a2 + a3);
      a[k] = ok ? fmaxf(acc, 0.f) : 0.f;
    }

    // 8 -> 32 matmul, pack to bf16, full-line store into plane z
    uint4* cp = (uint4*)(cat + ((size_t)z * NCH + (size_t)b * HWp + pix) * 32);
    #pragma unroll
    for (int q = 0; q < 4; ++q) {
      unsigned pw[4];
      #pragma unroll
      for (int pp = 0; pp < 4; ++pp) {
        int o = q * 8 + pp * 2;
        float h0 = 0.f, h1 = 0.f;
        #pragma unroll
        for (int k = 0; k < 8; ++k) {
          h0 = fmaf(a[k], w[o * 8 + k], h0);
          h1 = fmaf(a[k], w[(o + 1) * 8 + k], h1);
        }
        pw[pp] = pack2(h0, h1);
      }
      uint4 u; u.x = pw[0]; u.y = pw[1]; u.z = pw[2]; u.w = pw[3];
      cp[q] = u;
    }
  }
}

// ---------------- 3a. per-channel stats over split-plane bf16 cat ------------
// planes are [4][NCH][32]; 2048-pixel blocks never straddle a plane (NCH%2048==0)
__global__ __launch_bounds__(256) void k_stats_cat(const ushort_t* __restrict__ cat,
                                                   float* __restrict__ g_s,
                                                   float* __restrict__ g_q) {
  int t  = threadIdx.x;
  int cg = t & 3;               // 8-ch chunk: ch = cg*8
  int pr = t >> 2;              // 64 pixel streams
  int blk = blockIdx.x;         // 0..1599
  int z = blk / 400;            // plane
  size_t row0 = (size_t)blk * 2048 + pr;
  const uint4* base = (const uint4*)cat;     // 16B = 8 channels; 4 uint4 per row
  float s[8] = {0,0,0,0,0,0,0,0}, q[8] = {0,0,0,0,0,0,0,0};
  for (int j = 0; j < 32; ++j) {
    uint4 u = base[(row0 + (size_t)j * 64) * 4 + cg];
    float v[8]; unpack8(u, v);
    #pragma unroll
    for (int i = 0; i < 8; ++i) { s[i] += v[i]; q[i] = fmaf(v[i], v[i], q[i]); }
  }
  __shared__ float ls[64][32], lq[64][32];
  #pragma unroll
  for (int i = 0; i < 8; ++i) { ls[pr][cg*8+i] = s[i]; lq[pr][cg*8+i] = q[i]; }
  __syncthreads();
  if (t < 32) {
    float a = 0.f, bq = 0.f;
    for (int r = 0; r < 64; ++r) { a += ls[r][t]; bq += lq[r][t]; }
    atomicAdd(g_s + z * 32 + t, a); atomicAdd(g_q + z * 32 + t, bq);
  }
}

// ---------------- 3b. per-channel stats over fp32 channel-first tensor -------
__global__ __launch_bounds__(256) void k_stats_f32(const float* __restrict__ t,
                                                   float* __restrict__ g_s,
                                                   float* __restrict__ g_q) {
  int c = blockIdx.y, b = blockIdx.z;
  size_t base = ((size_t)b * 32 + c) * HWp + (size_t)blockIdx.x * 8192;
  const float4* p = (const float4*)(t + base) + threadIdx.x;
  float s = 0.f, q = 0.f;
  #pragma unroll
  for (int j = 0; j < 8; ++j) {
    float4 v = p[j * 256];
    s += v.x + v.y + v.z + v.w;
    q = fmaf(v.x, v.x, q); q = fmaf(v.y, v.y, q);
    q = fmaf(v.z, v.z, q); q = fmaf(v.w, v.w, q);
  }
  #pragma unroll
  for (int off = 32; off > 0; off >>= 1) {
    s += __shfl_down(s, off, 64);
    q += __shfl_down(q, off, 64);
  }
  __shared__ float ls[4], lq[4];
  int lane = threadIdx.x & 63, wid = threadIdx.x >> 6;
  if (lane == 0) { ls[wid] = s; lq[wid] = q; }
  __syncthreads();
  if (threadIdx.x == 0) {
    float ts = 0, tq = 0;
    #pragma unroll
    for (int i = 0; i < 4; ++i) { ts += ls[i]; tq += lq[i]; }
    atomicAdd(g_s + c, ts); atomicAdd(g_q + c, tq);
  }
}

// ---------------- 4. finalize BN scale/shift ----------------
__global__ void k_bnfin(const float* __restrict__ s, const float* __restrict__ q,
                        const float* g0, const float* g1, const float* g2, const float* g3,
                        const float* b0, const float* b1, const float* b2, const float* b3,
                        float* __restrict__ scale, float* __restrict__ shift, int Cc) {
  int c = threadIdx.x;
  if (c >= Cc) return;
  const float* g; const float* bb; int ci;
  if (Cc == 128) {
    int z = c >> 5; ci = c & 31;
    g  = (z == 0) ? g0 : (z == 1) ? g1 : (z == 2) ? g2 : g3;
    bb = (z == 0) ? b0 : (z == 1) ? b1 : (z == 2) ? b2 : b3;
  } else { g = g0; bb = b0; ci = c; }
  float mean = s[c] / (float)NCH;
  float var  = q[c] / (float)NCH - mean * mean;
  float inv  = 1.f / sqrtf(var + 1e-5f);
  float scv  = g[ci] * inv;
  scale[c] = scv;
  shift[c] = bb[ci] - mean * scv;
}

// ---------------- 5. weights -> bf16 MFMA B-fragment order -------------------
// wbf[((t*8 + cg)*64 + lane)*8 + j] = W[o=lane&31][ch=cg*16+(lane>>5)*8+j][tap t]
// ch is the GLOBAL 0..127 channel (z-major concat order) -- unchanged by the
// split-plane cat layout.
__global__ void k_wt(const float* __restrict__ wl, ushort_t* __restrict__ wbf) {
  int idx = blockIdx.x * 256 + threadIdx.x;
  if (idx >= 9 * 8 * 64 * 8) return;
  int j = idx & 7;
  int l = (idx >> 3) & 63;
  int tc = idx >> 9;                 // t*8 + cg
  int t = tc >> 3, cg = tc & 7;
  int o = l & 31;
  int ch = cg * 16 + ((l >> 5) << 3) + j;
  wbf[idx] = f2bf(wl[(o * 128 + ch) * 9 + t]);
}

// ---------------- 6. MFMA implicit-GEMM 3x3 conv 128->32 ---------------------
#define SROWS 6
#define SCOLS 34
#define CHPAD 72
__global__ __launch_bounds__(256, 4) void k_conv(const ushort_t* __restrict__ cat,
                                                 const ushort_t* __restrict__ wbf,
                                                 const float* __restrict__ scale,
                                                 const float* __restrict__ shift,
                                                 float* __restrict__ out) {
  __shared__ __align__(16) ushort_t s_in[SROWS * SCOLS * CHPAD];  // 29376 B
  int lane = threadIdx.x;            // 0..63
  int w    = threadIdx.y;            // 0..3
  int tid  = w * 64 + lane;
  int gx0 = blockIdx.x * 32, gy0 = blockIdx.y * 4;
  int b = blockIdx.z;
  size_t bHW = (size_t)b * HWp;

  const short8* wfr = (const short8*)wbf;
  float16v acc = {};

  int site0 = tid >> 3;              // 0..31
  int chp   = tid & 7;               // 16B chunk within 64 staged channels

  #pragma unroll
  for (int r = 0; r < 2; ++r) {
    int chb = r * 64 + chp * 8;      // global channel 0..127
    int zp  = chb >> 5;              // cat plane
    int chi = chb & 31;              // channel within plane
    const ushort_t* catz = cat + (size_t)zp * ((size_t)NCH * 32);
    float4 sc0 = *(const float4*)&scale[chb];
    float4 sc1 = *(const float4*)&scale[chb + 4];
    float4 sh0 = *(const float4*)&shift[chb];
    float4 sh1 = *(const float4*)&shift[chb + 4];
    float scl[8] = {sc0.x,sc0.y,sc0.z,sc0.w,sc1.x,sc1.y,sc1.z,sc1.w};
    float shf[8] = {sh0.x,sh0.y,sh0.z,sh0.w,sh1.x,sh1.y,sh1.z,sh1.w};

    if (r) __syncthreads();
    for (int s = site0; s < SROWS * SCOLS; s += 32) {
      int row = s / SCOLS, col = s - row * SCOLS;
      int gy = gy0 - 1 + row, gx = gx0 - 1 + col;
      uint4 u = {0u,0u,0u,0u};
      if ((unsigned)gy < (unsigned)HH && (unsigned)gx < (unsigned)WW) {
        uint4 raw = *(const uint4*)&catz[(bHW + (size_t)gy * WW + gx) * 32 + chi];
        unsigned rw[4] = {raw.x, raw.y, raw.z, raw.w};
        unsigned pk[4];
        #pragma unroll
        for (int q = 0; q < 4; ++q) {
          float v0 = fmaxf(fmaf(bf2f((ushort_t)(rw[q] & 0xffff)), scl[q*2],   shf[q*2]),   0.f);
          float v1 = fmaxf(fmaf(bf2f((ushort_t)(rw[q] >> 16)),    scl[q*2+1], shf[q*2+1]), 0.f);
          pk[q] = pack2(v0, v1);
        }
        u.x = pk[0]; u.y = pk[1]; u.z = pk[2]; u.w = pk[3];
      }
      *(uint4*)&s_in[(size_t)s * CHPAD + chp * 8] = u;
    }
    __syncthreads();

    int pcol = lane & 31;
    int half = lane >> 5;
    #pragma unroll
    for (int t = 0; t < 9; ++t) {
      int ky = t / 3, kx = t - ky * 3;
      int rowbase = ((w + ky) * SCOLS + pcol + kx) * CHPAD + half * 8;
      #pragma unroll
      for (int c = 0; c < 4; ++c) {
        short8 bfrag = wfr[(t * 8 + r * 4 + c) * 64 + lane];
        short8 afrag = *(const short8*)&s_in[rowbase + c * 16];
        acc = __builtin_amdgcn_mfma_f32_32x32x16_bf16(afrag, bfrag, acc, 0, 0, 0);
      }
    }
  }

  // epilogue: transpose C tile through LDS for coalesced channel-first stores
  __syncthreads();
  float* epi = (float*)s_in + w * (32 * 33);
  int half = lane >> 5, mm = lane & 31;
  #pragma unroll
  for (int r16 = 0; r16 < 16; ++r16) {
    int m = (r16 & 3) + 8 * (r16 >> 2) + 4 * half;
    epi[m * 33 + mm] = acc[r16];
  }
  __syncthreads();
  size_t obase = bHW + (size_t)(gy0 + w) * WW + gx0 + mm;
  #pragma unroll
  for (int i = 0; i < 16; ++i) {
    int o = half * 16 + i;
    out[(size_t)o * HWp + obase + (size_t)b * (CHWp - HWp)] = epi[mm * 33 + o];
  }
}

// ---------------- 7. BN2 + ReLU + 32x32 matmul, in-place on d_out ------------
// float2: 2 pixels per thread
__global__ __launch_bounds__(256) void k_final(const float* hin,
                                               const float* __restrict__ wf,
                                               const float* __restrict__ scale,
                                               const float* __restrict__ shift,
                                               float* out) {
  int p2 = blockIdx.x * 256 + threadIdx.x;
  int b  = blockIdx.y;
  const float2* hp = (const float2*)(hin + (size_t)b * CHWp) + p2;
  float va[32], vb[32];
  #pragma unroll
  for (int c = 0; c < 32; ++c) {
    float2 v = hp[c * (HWp/2)];
    va[c] = fmaxf(fmaf(v.x, scale[c], shift[c]), 0.f);
    vb[c] = fmaxf(fmaf(v.y, scale[c], shift[c]), 0.f);
  }
  float2* op = (float2*)(out + (size_t)b * CHWp) + p2;
  #pragma unroll
  for (int o = 0; o < 32; ++o) {
    float ra = 0.f, rb = 0.f;
    #pragma unroll
    for (int c = 0; c < 32; ++c) {
      float wv = wf[o * 32 + c];
      ra = fmaf(va[c], wv, ra);
      rb = fmaf(vb[c], wv, rb);
    }
    float2 rr; rr.x = ra; rr.y = rb;
    op[o * (HWp/2)] = rr;
  }
}

extern "C" void kernel_launch(void* const* d_in, const int* in_sizes, int n_in,
                              void* d_out, int out_size, void* d_ws, size_t ws_size,
                              hipStream_t stream) {
  const float* x      = (const float*)d_in[0];
  const float* w1     = (const float*)d_in[1];
  const float* g1     = (const float*)d_in[2];
  const float* b1     = (const float*)d_in[3];
  const float* w2     = (const float*)d_in[4];
  const float* g2     = (const float*)d_in[5];
  const float* b2     = (const float*)d_in[6];
  const float* w3     = (const float*)d_in[7];
  const float* g3     = (const float*)d_in[8];
  const float* b3     = (const float*)d_in[9];
  const float* w4     = (const float*)d_in[10];
  const float* g4     = (const float*)d_in[11];
  const float* b4     = (const float*)d_in[12];
  const float* w_last = (const float*)d_in[13];
  const float* g_last = (const float*)d_in[14];
  const float* b_last = (const float*)d_in[15];
  const float* w_fin  = (const float*)d_in[16];

  float* ws = (float*)d_ws;
  ushort_t* wbf = (ushort_t*)(ws + WT_OFF);
  float*    st  = ws + ST_OFF;
  float*    sc  = ws + SC_OFF;
  ushort_t* cat = (ushort_t*)(ws + CATF_OFF);

  float* xn = (float*)d_out;  // d_out: fp32 xn -> fp32 conv-out -> final out

  hipMemsetAsync(st, 0, 320 * sizeof(float), stream);

  k_normalize<<<dim3(400, 4), 256, 0, stream>>>(x, xn);
  k_branch_all<<<dim3(800, 4), 256, 0, stream>>>(xn, w1, w2, w3, w4, cat);
  k_stats_cat<<<1600, 256, 0, stream>>>(cat, st, st + 128);
  k_bnfin<<<1, 128, 0, stream>>>(st, st + 128, g1, g2, g3, g4, b1, b2, b3, b4,
                                 sc, sc + 128, 128);
  k_wt<<<144, 256, 0, stream>>>(w_last, wbf);
  k_conv<<<dim3(20, 80, 4), dim3(64, 4), 0, stream>>>(cat, wbf, sc, sc + 128, xn);
  k_stats_f32<<<dim3(25, 32, 4), 256, 0, stream>>>(xn, st + 256, st + 288);
  k_bnfin<<<1, 128, 0, stream>>>(st + 256, st + 288, g_last, g_last, g_last, g_last,
                                 b_last, b_last, b_last, b_last, sc + 256, sc + 288, 32);
  k_final<<<dim3(400, 4), 256, 0, stream>>>(xn, w_fin, sc + 256, sc + 288, (float*)d_out);
}

// Round 5
// 580.814 us; speedup vs baseline: 2.0408x; 1.8542x over previous
//
#include <hip/hip_runtime.h>
#include <math.h>

#define BB 4
#define CC0 32
#define HH 320
#define WW 640
#define HWp (HH*WW)          // 204800
#define CHWp (CC0*HWp)       // 6553600
#define NCH (BB*HWp)         // 819200
#define CCAT 128

// ---------------- workspace layout ----------------
// wbf (ushort, MFMA B-frag order): 36864 ushorts at float-offset 0 (73728 B)
// st  floats [36864,37184): s1[128] q1[128] s2[32] q2[32]
// sc  floats [37184,37504): scale1[128] shift1[128] scale2[32] shift2[32]
// cat bf16 SPLIT PLANES [z][b][pix][32]: 104,857,600 elems from float-offset 37504
#define WT_OFF  ((size_t)0)
#define ST_OFF  ((size_t)36864)
#define SC_OFF  ((size_t)37184)
#define CATF_OFF ((size_t)37504)

typedef unsigned short ushort_t;
typedef __attribute__((ext_vector_type(8)))  short    short8;
typedef __attribute__((ext_vector_type(16))) float    float16v;
typedef _Float16 h8 __attribute__((ext_vector_type(8)));   // 4 VGPRs, pk-math
typedef _Float16 h2 __attribute__((ext_vector_type(2)));

static __device__ __forceinline__ float bf2f(ushort_t u) {
  unsigned x = ((unsigned)u) << 16;
  float f; __builtin_memcpy(&f, &x, 4); return f;
}
static __device__ __forceinline__ ushort_t f2bf(float f) {
  unsigned x; __builtin_memcpy(&x, &f, 4);
  unsigned r = (x + 0x7fffu + ((x >> 16) & 1u)) >> 16;   // RNE
  return (ushort_t)r;
}
static __device__ __forceinline__ unsigned pack2(float a, float b) {
  return (unsigned)f2bf(a) | ((unsigned)f2bf(b) << 16);
}
static __device__ __forceinline__ unsigned pack2h(float a, float b) {
  h2 t; t[0] = (_Float16)a; t[1] = (_Float16)b;
  unsigned u; __builtin_memcpy(&u, &t, 4); return u;
}
static __device__ __forceinline__ void unpack8(uint4 u, float* f) {
  f[0] = bf2f((ushort_t)(u.x & 0xffff)); f[1] = bf2f((ushort_t)(u.x >> 16));
  f[2] = bf2f((ushort_t)(u.y & 0xffff)); f[3] = bf2f((ushort_t)(u.y >> 16));
  f[4] = bf2f((ushort_t)(u.z & 0xffff)); f[5] = bf2f((ushort_t)(u.z >> 16));
  f[6] = bf2f((ushort_t)(u.w & 0xffff)); f[7] = bf2f((ushort_t)(u.w >> 16));
}

// ---------------- 1. L2 normalize -> fp16 channel-LAST xn (into d_out) -------
// fp16 (2^-11) is more accurate than the bf16 we shipped before, and enables
// pk_fma dot products with zero unpack VALU in k_branch.
__global__ __launch_bounds__(256) void k_normalize(const float* __restrict__ x,
                                                   ushort_t* __restrict__ xnh) {
  int p2 = blockIdx.x * 256 + threadIdx.x;     // pixel-pair index
  int b  = blockIdx.y;
  const float2* xp = (const float2*)(x + (size_t)b * CHWp) + p2;
  float va[32], vb[32];
  float sa = 0.f, sb = 0.f;
  #pragma unroll
  for (int c = 0; c < 32; ++c) {
    float2 v = xp[c * (HWp/2)];
    va[c] = v.x; vb[c] = v.y;
    sa = fmaf(v.x, v.x, sa); sb = fmaf(v.y, v.y, sb);
  }
  float ia = 1.f / fmaxf(sqrtf(sa), 1e-12f);
  float ib = 1.f / fmaxf(sqrtf(sb), 1e-12f);
  uint4* op = (uint4*)(xnh + ((size_t)b * HWp + (size_t)p2 * 2) * 32);
  #pragma unroll
  for (int q = 0; q < 4; ++q) {
    uint4 u;
    u.x = pack2h(va[q*8+0]*ia, va[q*8+1]*ia);
    u.y = pack2h(va[q*8+2]*ia, va[q*8+3]*ia);
    u.z = pack2h(va[q*8+4]*ia, va[q*8+5]*ia);
    u.w = pack2h(va[q*8+6]*ia, va[q*8+7]*ia);
    op[q] = u;
  }
  #pragma unroll
  for (int q = 0; q < 4; ++q) {
    uint4 u;
    u.x = pack2h(vb[q*8+0]*ib, vb[q*8+1]*ib);
    u.y = pack2h(vb[q*8+2]*ib, vb[q*8+3]*ib);
    u.z = pack2h(vb[q*8+4]*ib, vb[q*8+5]*ib);
    u.w = pack2h(vb[q*8+6]*ib, vb[q*8+7]*ib);
    op[4 + q] = u;
  }
}

// ---------------- 2. affinity + 8->32 matmul, one dilation per z-block -------
// Round-0 structure (z-in-grid, 12800 blocks = the latency hider) + three
// fixes: XCD-contiguous swizzle (L2 locality), fp16 pk_fma dot (no unpack,
// ~22 VALU/tap vs ~64), split-plane full-line stores.
__global__ __launch_bounds__(256, 4) void k_branch(const ushort_t* __restrict__ xnh,
                                                   const float* __restrict__ w0,
                                                   const float* __restrict__ w1,
                                                   const float* __restrict__ w2,
                                                   const float* __restrict__ w3,
                                                   ushort_t* __restrict__ cat) {
  int z = blockIdx.z;
  int d = 1 << z;
  const float* w = (z == 0) ? w0 : (z == 1) ? w1 : (z == 2) ? w2 : w3;
  int bx = blockIdx.x;
  bx = (bx & 7) * 100 + (bx >> 3);       // 800 = 8 XCDs * 100 contiguous chunks
  int pix = bx * 256 + threadIdx.x;
  int b   = blockIdx.y;
  int y = pix / WW;
  int x = pix - y * WW;

  const ushort_t* cp0 = xnh + ((size_t)b * HWp + pix) * 32;
  h8 cen[4];
  {
    const h8* cv = (const h8*)cp0;
    #pragma unroll
    for (int q = 0; q < 4; ++q) cen[q] = cv[q];
  }

  const int DY[8] = {-1,-1,-1, 0, 0, 1, 1, 1};
  const int DX[8] = {-1, 0, 1,-1, 1,-1, 0, 1};
  float a[8];
  #pragma unroll
  for (int k = 0; k < 8; ++k) {
    int dy = DY[k] * d, dx = DX[k] * d;
    bool ok = ((unsigned)(y + dy) < (unsigned)HH) && ((unsigned)(x + dx) < (unsigned)WW);
    int ofs = ok ? (dy * WW + dx) : 0;     // OOB -> read own pixel, masked
    const h8* np = (const h8*)(cp0 + (ptrdiff_t)ofs * 32);
    h8 n0 = np[0], n1 = np[1], n2 = np[2], n3 = np[3];
    h8 p = __builtin_elementwise_fma(cen[1], n1, cen[0] * n0);
    p = __builtin_elementwise_fma(cen[2], n2, p);
    p = __builtin_elementwise_fma(cen[3], n3, p);
    // horizontal reduce 8 halves (all partials bounded by 1: Cauchy-Schwarz)
    h2 t0 = __builtin_shufflevector(p, p, 0, 1);
    h2 t1 = __builtin_shufflevector(p, p, 2, 3);
    h2 t2 = __builtin_shufflevector(p, p, 4, 5);
    h2 t3 = __builtin_shufflevector(p, p, 6, 7);
    h2 t = (t0 + t1) + (t2 + t3);
    float aff = (float)t[0] + (float)t[1];
    a[k] = ok ? fmaxf(aff, 0.f) : 0.f;
  }

  // 8 -> 32 matmul (fp32 weights), pack to bf16, full-line store into plane z
  uint4* cp = (uint4*)(cat + ((size_t)z * NCH + (size_t)b * HWp + pix) * 32);
  #pragma unroll
  for (int q = 0; q < 4; ++q) {
    unsigned pw[4];
    #pragma unroll
    for (int pp = 0; pp < 4; ++pp) {
      int o = q * 8 + pp * 2;
      float h0 = 0.f, h1 = 0.f;
      #pragma unroll
      for (int k = 0; k < 8; ++k) {
        h0 = fmaf(a[k], w[o * 8 + k], h0);
        h1 = fmaf(a[k], w[(o + 1) * 8 + k], h1);
      }
      pw[pp] = pack2(h0, h1);
    }
    uint4 u; u.x = pw[0]; u.y = pw[1]; u.z = pw[2]; u.w = pw[3];
    cp[q] = u;
  }
}

// ---------------- 3a. per-channel stats over split-plane bf16 cat ------------
// planes are [4][NCH][32]; 2048-pixel blocks never straddle a plane (NCH%2048==0)
__global__ __launch_bounds__(256) void k_stats_cat(const ushort_t* __restrict__ cat,
                                                   float* __restrict__ g_s,
                                                   float* __restrict__ g_q) {
  int t  = threadIdx.x;
  int cg = t & 3;               // 8-ch chunk: ch = cg*8
  int pr = t >> 2;              // 64 pixel streams
  int blk = blockIdx.x;         // 0..1599
  int z = blk / 400;            // plane
  size_t row0 = (size_t)blk * 2048 + pr;
  const uint4* base = (const uint4*)cat;     // 16B = 8 channels; 4 uint4 per row
  float s[8] = {0,0,0,0,0,0,0,0}, q[8] = {0,0,0,0,0,0,0,0};
  for (int j = 0; j < 32; ++j) {
    uint4 u = base[(row0 + (size_t)j * 64) * 4 + cg];
    float v[8]; unpack8(u, v);
    #pragma unroll
    for (int i = 0; i < 8; ++i) { s[i] += v[i]; q[i] = fmaf(v[i], v[i], q[i]); }
  }
  __shared__ float ls[64][32], lq[64][32];
  #pragma unroll
  for (int i = 0; i < 8; ++i) { ls[pr][cg*8+i] = s[i]; lq[pr][cg*8+i] = q[i]; }
  __syncthreads();
  if (t < 32) {
    float a = 0.f, bq = 0.f;
    for (int r = 0; r < 64; ++r) { a += ls[r][t]; bq += lq[r][t]; }
    atomicAdd(g_s + z * 32 + t, a); atomicAdd(g_q + z * 32 + t, bq);
  }
}

// ---------------- 3b. per-channel stats over fp32 channel-first tensor -------
__global__ __launch_bounds__(256) void k_stats_f32(const float* __restrict__ t,
                                                   float* __restrict__ g_s,
                                                   float* __restrict__ g_q) {
  int c = blockIdx.y, b = blockIdx.z;
  size_t base = ((size_t)b * 32 + c) * HWp + (size_t)blockIdx.x * 8192;
  const float4* p = (const float4*)(t + base) + threadIdx.x;
  float s = 0.f, q = 0.f;
  #pragma unroll
  for (int j = 0; j < 8; ++j) {
    float4 v = p[j * 256];
    s += v.x + v.y + v.z + v.w;
    q = fmaf(v.x, v.x, q); q = fmaf(v.y, v.y, q);
    q = fmaf(v.z, v.z, q); q = fmaf(v.w, v.w, q);
  }
  #pragma unroll
  for (int off = 32; off > 0; off >>= 1) {
    s += __shfl_down(s, off, 64);
    q += __shfl_down(q, off, 64);
  }
  __shared__ float ls[4], lq[4];
  int lane = threadIdx.x & 63, wid = threadIdx.x >> 6;
  if (lane == 0) { ls[wid] = s; lq[wid] = q; }
  __syncthreads();
  if (threadIdx.x == 0) {
    float ts = 0, tq = 0;
    #pragma unroll
    for (int i = 0; i < 4; ++i) { ts += ls[i]; tq += lq[i]; }
    atomicAdd(g_s + c, ts); atomicAdd(g_q + c, tq);
  }
}

// ---------------- 4. finalize BN scale/shift ----------------
__global__ void k_bnfin(const float* __restrict__ s, const float* __restrict__ q,
                        const float* g0, const float* g1, const float* g2, const float* g3,
                        const float* b0, const float* b1, const float* b2, const float* b3,
                        float* __restrict__ scale, float* __restrict__ shift, int Cc) {
  int c = threadIdx.x;
  if (c >= Cc) return;
  const float* g; const float* bb; int ci;
  if (Cc == 128) {
    int z = c >> 5; ci = c & 31;
    g  = (z == 0) ? g0 : (z == 1) ? g1 : (z == 2) ? g2 : g3;
    bb = (z == 0) ? b0 : (z == 1) ? b1 : (z == 2) ? b2 : b3;
  } else { g = g0; bb = b0; ci = c; }
  float mean = s[c] / (float)NCH;
  float var  = q[c] / (float)NCH - mean * mean;
  float inv  = 1.f / sqrtf(var + 1e-5f);
  float scv  = g[ci] * inv;
  scale[c] = scv;
  shift[c] = bb[ci] - mean * scv;
}

// ---------------- 5. weights -> bf16 MFMA B-fragment order -------------------
// wbf[((t*8 + cg)*64 + lane)*8 + j] = W[o=lane&31][ch=cg*16+(lane>>5)*8+j][tap t]
// ch is the GLOBAL 0..127 channel (z-major concat order).
__global__ void k_wt(const float* __restrict__ wl, ushort_t* __restrict__ wbf) {
  int idx = blockIdx.x * 256 + threadIdx.x;
  if (idx >= 9 * 8 * 64 * 8) return;
  int j = idx & 7;
  int l = (idx >> 3) & 63;
  int tc = idx >> 9;                 // t*8 + cg
  int t = tc >> 3, cg = tc & 7;
  int o = l & 31;
  int ch = cg * 16 + ((l >> 5) << 3) + j;
  wbf[idx] = f2bf(wl[(o * 128 + ch) * 9 + t]);
}

// ---------------- 6. MFMA implicit-GEMM 3x3 conv 128->32 ---------------------
#define SROWS 6
#define SCOLS 34
#define CHPAD 72
__global__ __launch_bounds__(256, 4) void k_conv(const ushort_t* __restrict__ cat,
                                                 const ushort_t* __restrict__ wbf,
                                                 const float* __restrict__ scale,
                                                 const float* __restrict__ shift,
                                                 float* __restrict__ out) {
  __shared__ __align__(16) ushort_t s_in[SROWS * SCOLS * CHPAD];  // 29376 B
  int lane = threadIdx.x;            // 0..63
  int w    = threadIdx.y;            // 0..3
  int tid  = w * 64 + lane;
  int gx0 = blockIdx.x * 32, gy0 = blockIdx.y * 4;
  int b = blockIdx.z;
  size_t bHW = (size_t)b * HWp;

  const short8* wfr = (const short8*)wbf;
  float16v acc = {};

  int site0 = tid >> 3;              // 0..31
  int chp   = tid & 7;               // 16B chunk within 64 staged channels

  #pragma unroll
  for (int r = 0; r < 2; ++r) {
    int chb = r * 64 + chp * 8;      // global channel 0..127
    int zp  = chb >> 5;              // cat plane
    int chi = chb & 31;              // channel within plane
    const ushort_t* catz = cat + (size_t)zp * ((size_t)NCH * 32);
    float4 sc0 = *(const float4*)&scale[chb];
    float4 sc1 = *(const float4*)&scale[chb + 4];
    float4 sh0 = *(const float4*)&shift[chb];
    float4 sh1 = *(const float4*)&shift[chb + 4];
    float scl[8] = {sc0.x,sc0.y,sc0.z,sc0.w,sc1.x,sc1.y,sc1.z,sc1.w};
    float shf[8] = {sh0.x,sh0.y,sh0.z,sh0.w,sh1.x,sh1.y,sh1.z,sh1.w};

    if (r) __syncthreads();
    for (int s = site0; s < SROWS * SCOLS; s += 32) {
      int row = s / SCOLS, col = s - row * SCOLS;
      int gy = gy0 - 1 + row, gx = gx0 - 1 + col;
      uint4 u = {0u,0u,0u,0u};
      if ((unsigned)gy < (unsigned)HH && (unsigned)gx < (unsigned)WW) {
        uint4 raw = *(const uint4*)&catz[(bHW + (size_t)gy * WW + gx) * 32 + chi];
        unsigned rw[4] = {raw.x, raw.y, raw.z, raw.w};
        unsigned pk[4];
        #pragma unroll
        for (int q = 0; q < 4; ++q) {
          float v0 = fmaxf(fmaf(bf2f((ushort_t)(rw[q] & 0xffff)), scl[q*2],   shf[q*2]),   0.f);
          float v1 = fmaxf(fmaf(bf2f((ushort_t)(rw[q] >> 16)),    scl[q*2+1], shf[q*2+1]), 0.f);
          pk[q] = pack2(v0, v1);
        }
        u.x = pk[0]; u.y = pk[1]; u.z = pk[2]; u.w = pk[3];
      }
      *(uint4*)&s_in[(size_t)s * CHPAD + chp * 8] = u;
    }
    __syncthreads();

    int pcol = lane & 31;
    int half = lane >> 5;
    #pragma unroll
    for (int t = 0; t < 9; ++t) {
      int ky = t / 3, kx = t - ky * 3;
      int rowbase = ((w + ky) * SCOLS + pcol + kx) * CHPAD + half * 8;
      #pragma unroll
      for (int c = 0; c < 4; ++c) {
        short8 bfrag = wfr[(t * 8 + r * 4 + c) * 64 + lane];
        short8 afrag = *(const short8*)&s_in[rowbase + c * 16];
        acc = __builtin_amdgcn_mfma_f32_32x32x16_bf16(afrag, bfrag, acc, 0, 0, 0);
      }
    }
  }

  // epilogue: transpose C tile through LDS for coalesced channel-first stores
  __syncthreads();
  float* epi = (float*)s_in + w * (32 * 33);
  int half = lane >> 5, mm = lane & 31;
  #pragma unroll
  for (int r16 = 0; r16 < 16; ++r16) {
    int m = (r16 & 3) + 8 * (r16 >> 2) + 4 * half;
    epi[m * 33 + mm] = acc[r16];
  }
  __syncthreads();
  size_t obase = bHW + (size_t)(gy0 + w) * WW + gx0 + mm;
  #pragma unroll
  for (int i = 0; i < 16; ++i) {
    int o = half * 16 + i;
    out[(size_t)o * HWp + obase + (size_t)b * (CHWp - HWp)] = epi[mm * 33 + o];
  }
}

// ---------------- 7. BN2 + ReLU + 32x32 matmul, in-place on d_out ------------
// float2: 2 pixels per thread
__global__ __launch_bounds__(256) void k_final(const float* hin,
                                               const float* __restrict__ wf,
                                               const float* __restrict__ scale,
                                               const float* __restrict__ shift,
                                               float* out) {
  int p2 = blockIdx.x * 256 + threadIdx.x;
  int b  = blockIdx.y;
  const float2* hp = (const float2*)(hin + (size_t)b * CHWp) + p2;
  float va[32], vb[32];
  #pragma unroll
  for (int c = 0; c < 32; ++c) {
    float2 v = hp[c * (HWp/2)];
    va[c] = fmaxf(fmaf(v.x, scale[c], shift[c]), 0.f);
    vb[c] = fmaxf(fmaf(v.y, scale[c], shift[c]), 0.f);
  }
  float2* op = (float2*)(out + (size_t)b * CHWp) + p2;
  #pragma unroll
  for (int o = 0; o < 32; ++o) {
    float ra = 0.f, rb = 0.f;
    #pragma unroll
    for (int c = 0; c < 32; ++c) {
      float wv = wf[o * 32 + c];
      ra = fmaf(va[c], wv, ra);
      rb = fmaf(vb[c], wv, rb);
    }
    float2 rr; rr.x = ra; rr.y = rb;
    op[o * (HWp/2)] = rr;
  }
}

extern "C" void kernel_launch(void* const* d_in, const int* in_sizes, int n_in,
                              void* d_out, int out_size, void* d_ws, size_t ws_size,
                              hipStream_t stream) {
  const float* x      = (const float*)d_in[0];
  const float* w1     = (const float*)d_in[1];
  const float* g1     = (const float*)d_in[2];
  const float* b1     = (const float*)d_in[3];
  const float* w2     = (const float*)d_in[4];
  const float* g2     = (const float*)d_in[5];
  const float* b2     = (const float*)d_in[6];
  const float* w3     = (const float*)d_in[7];
  const float* g3     = (const float*)d_in[8];
  const float* b3     = (const float*)d_in[9];
  const float* w4     = (const float*)d_in[10];
  const float* g4     = (const float*)d_in[11];
  const float* b4     = (const float*)d_in[12];
  const float* w_last = (const float*)d_in[13];
  const float* g_last = (const float*)d_in[14];
  const float* b_last = (const float*)d_in[15];
  const float* w_fin  = (const float*)d_in[16];

  float* ws = (float*)d_ws;
  ushort_t* wbf = (ushort_t*)(ws + WT_OFF);
  float*    st  = ws + ST_OFF;
  float*    sc  = ws + SC_OFF;
  ushort_t* cat = (ushort_t*)(ws + CATF_OFF);

  ushort_t* xnh = (ushort_t*)d_out;  // d_out: fp16 xn -> fp32 conv-out -> final out
  float*    xn  = (float*)d_out;

  hipMemsetAsync(st, 0, 320 * sizeof(float), stream);

  k_normalize<<<dim3(400, 4), 256, 0, stream>>>(x, xnh);
  k_branch<<<dim3(800, 4, 4), 256, 0, stream>>>(xnh, w1, w2, w3, w4, cat);
  k_stats_cat<<<1600, 256, 0, stream>>>(cat, st, st + 128);
  k_bnfin<<<1, 128, 0, stream>>>(st, st + 128, g1, g2, g3, g4, b1, b2, b3, b4,
                                 sc, sc + 128, 128);
  k_wt<<<144, 256, 0, stream>>>(w_last, wbf);
  k_conv<<<dim3(20, 80, 4), dim3(64, 4), 0, stream>>>(cat, wbf, sc, sc + 128, xn);
  k_stats_f32<<<dim3(25, 32, 4), 256, 0, stream>>>(xn, st + 256, st + 288);
  k_bnfin<<<1, 128, 0, stream>>>(st + 256, st + 288, g_last, g_last, g_last, g_last,
                                 b_last, b_last, b_last, b_last, sc + 256, sc + 288, 32);
  k_final<<<dim3(400, 4), 256, 0, stream>>>(xn, w_fin, sc + 256, sc + 288, (float*)d_out);
}